// Round 13
// baseline (204.321 us; speedup 1.0000x reference)
//
#include <hip/hip_runtime.h>

// SimpleSNN: T=16, B=4096, N_IN=784, N_HID=256, N_OUT=10
//   conv_x      : X fp32 {0,1} -> Xq4T nibbles in TILED layout
//                 [t][b/16][kt][r=b%16][32B]  (wave reads 512B contiguous)
//   conv_w3     : W1 -> 3 i8 planes, w = 2^-11 a + 2^-18 b + 2^-25 c
//   gemm1_lif1  : FUSED, t-tiled x4, 64r x 32c blocks, W in LDS once,
//                 zero barriers in loop; A loads fully coalesced; spikes
//                 written TRANSPOSED Z1T[n][m] as packed u32 (nontemporal,
//                 no cross-block false sharing).
//   gemm2_f32   : C2T[o][m] = b2 + sum_n Z1T[n][m]*W2[o][n]; groups-of-4
//                 ascending-n expression (same fp order as prior rounds)
//   lif2        : reads C2T, thread = (o,b)

#define T_STEPS 16
#define B_SZ    4096
#define N_IN    784
#define N_HID   256
#define N_OUT   10
#define M_TOT   (T_STEPS * B_SZ)   // 65536
#define KP8     832                // 13 * 64
#define KNB     416                // nibble bytes per row
#define NKT     13                 // K=64 steps
#define WPLANE  (N_HID * KP8)      // i8 elems per W plane (global)
#define WROW    848                // padded LDS row stride (53*16)
#define WPL     (32 * WROW)        // per-plane LDS bytes (27136)
#define TSH     ((size_t)256 * NKT * 512)   // Xq4T per-t stride = 1,703,936 B

typedef int    i32x4 __attribute__((ext_vector_type(4)));
typedef unsigned int u32;
typedef unsigned char u8;

#if defined(__has_builtin) && __has_builtin(__builtin_amdgcn_perm)
__device__ __forceinline__ u32 ilv(u32 hi, u32 lo) {
    return __builtin_amdgcn_perm(hi, lo, 0x05010400u);
}
__device__ __forceinline__ u32 ilv_hi(u32 hi, u32 lo) {
    return __builtin_amdgcn_perm(hi, lo, 0x07030602u);
}
#else
__device__ __forceinline__ u32 ilv(u32 hi, u32 lo) {
    return (lo & 0xFFu) | ((hi & 0xFFu) << 8) |
           ((lo & 0xFF00u) << 8) | ((hi & 0xFF00u) << 16);
}
__device__ __forceinline__ u32 ilv_hi(u32 hi, u32 lo) { return ilv(hi >> 16, lo >> 16); }
#endif

// unpack 8 nibble-bytes (16 k-values) -> 16 i8 bytes {0,1}
__device__ __forceinline__ uint4 unp(uint2 u) {
    const u32 lo0 = u.x & 0x0F0F0F0Fu, hi0 = (u.x >> 4) & 0x0F0F0F0Fu;
    const u32 lo1 = u.y & 0x0F0F0F0Fu, hi1 = (u.y >> 4) & 0x0F0F0F0Fu;
    uint4 r;
    r.x = ilv(hi0, lo0);
    r.y = ilv_hi(hi0, lo0);
    r.z = ilv(hi1, lo1);
    r.w = ilv_hi(hi1, lo1);
    return r;
}

// ---------------- conv_x: fp32 {0,1} -> Xq4T tiled nibbles -----------------
__global__ __launch_bounds__(256) void conv_x(
    const float* __restrict__ X, u8* __restrict__ Xq4T)
{
    const int idx = blockIdx.x * 256 + threadIdx.x;   // < 65536*52 (uint2 units)
    const int q  = idx & 63;          // r*4 + ls within a (t,bg,kt) 512B unit
    const int h  = idx >> 6;          // (t*256+bg)*13 + kt
    const int kt = h % NKT;
    const int u  = h / NKT;           // t*256 + bg
    const int bg = u & 255;
    const int t  = u >> 8;
    const int r  = q >> 2;
    const int ls = q & 3;
    const long m  = (long)t * B_SZ + bg * 16 + r;
    const int k0 = kt * 64 + ls * 16;
    uint2 o = make_uint2(0u, 0u);
    if (k0 + 16 <= N_IN) {            // full 16-chunk valid or fully padded
        const uint4* src = reinterpret_cast<const uint4*>(X + m * N_IN + k0);
        const uint4 f0 = src[0], f1 = src[1], f2 = src[2], f3 = src[3];
        auto nib = [](uint4 a, uint4 b) -> u32 {
            return (a.x ? 1u : 0u)        | ((a.y ? 1u : 0u) << 4)  |
                   ((a.z ? 1u : 0u) << 8) | ((a.w ? 1u : 0u) << 12) |
                   ((b.x ? 1u : 0u) << 16)| ((b.y ? 1u : 0u) << 20) |
                   ((b.z ? 1u : 0u) << 24)| ((b.w ? 1u : 0u) << 28);
        };
        o.x = nib(f0, f1);
        o.y = nib(f2, f3);
    }
    reinterpret_cast<uint2*>(Xq4T)[idx] = o;
}

// ---------------- conv_w3: W1 -> 3 i8 planes (power-of-2 scales) -----------
__global__ __launch_bounds__(256) void conv_w3(
    const float* __restrict__ W1, char* __restrict__ Wq)
{
    const int idx = blockIdx.x * 256 + threadIdx.x;   // over 256*832
    if (idx >= N_HID * KP8) return;
    const int n = idx / KP8, k = idx % KP8;
    const float w = (k < N_IN) ? W1[n * N_IN + k] : 0.0f;
    const float a = rintf(w * 2048.0f);                       // s1 = 2^-11
    const float r1 = fmaf(a, -4.8828125e-4f, w);
    const float b = rintf(r1 * 262144.0f);                    // s2 = 2^-18
    const float r2 = fmaf(b, -3.814697265625e-6f, r1);
    const float c = rintf(r2 * 33554432.0f);                  // s3 = 2^-25
    Wq[idx]              = (char)(int)a;
    Wq[WPLANE + idx]     = (char)(int)b;
    Wq[2 * WPLANE + idx] = (char)(int)c;
}

// ---------------- gemm1 + lif1 fused, tiled A, t-tiled x4, Z1T out ---------
__global__ __launch_bounds__(256, 2) void gemm1_lif1(
    const u8* __restrict__ Xq4T,
    const u8* __restrict__ Wq,
    const float* __restrict__ b1,
    u8* __restrict__ Z1T)
{
    __shared__ u8 Bq[3 * WPL];          // 81,408 B -> 2 blocks/CU

    const int tid  = threadIdx.x;
    const int lane = tid & 63;
    const int w    = tid >> 6;          // wave 0..3: rows w*16..+16
    // XCD grouping: 8 b-tiles x 8 n-slices per XCD
    const int bid = blockIdx.x;
    const int l   = (bid & 7) * 64 + (bid >> 3);
    const int b0  = (l >> 3) * 64;      // b-tile of 64 rows
    const int n0  = (l & 7) * 32;       // n-slice of 32 cols
    const int ls  = lane >> 4;          // k-slot 0..3 (8B each)
    const int lr  = lane & 15;

    // ---- W -> LDS via regs ----
    #pragma unroll
    for (int it = 0; it < 20; ++it) {
        const int u = it * 256 + tid;                 // 3*32*52 = 4992 units
        if (u < 4992) {
            const int plane = u / 1664;
            const int rem   = u - plane * 1664;
            const int col   = rem / 52;
            const int sp    = rem - col * 52;
            const uint4 v = *reinterpret_cast<const uint4*>(
                Wq + (size_t)plane * WPLANE + (size_t)(n0 + col) * KP8 + sp * 16);
            *reinterpret_cast<uint4*>(&Bq[plane * WPL + col * WROW + sp * 16]) = v;
        }
    }
    __syncthreads();                    // the only barrier

    const float bb0 = b1[n0 + lr];
    const float bb1 = b1[n0 + 16 + lr];
    float vS[8], cS[8];                 // LIF state per (cf,q)
    #pragma unroll
    for (int k = 0; k < 8; ++k) { vS[k] = 0.0f; cS[k] = 0.0f; }

    int bO[2][3];
    #pragma unroll
    for (int cf = 0; cf < 2; ++cf)
        #pragma unroll
        for (int p = 0; p < 3; ++p)
            bO[cf][p] = p * WPL + (cf * 16 + lr) * WROW + (ls << 4);

    const int bg = (b0 >> 4) + w;       // this wave's 16-row group
    const u8* aP = Xq4T + (size_t)bg * (NKT * 512) + lr * 32 + ls * 8;

    const float s1 = 4.8828125e-4f;          // 2^-11
    const float s2 = 3.814697265625e-6f;     // 2^-18
    const float s3 = 2.9802322387695312e-8f; // 2^-25

    for (int g = 0; g < 4; ++g) {       // 4 groups x 4 timesteps
        i32x4 acc[4][2][3];
        #pragma unroll
        for (int tt = 0; tt < 4; ++tt)
            #pragma unroll
            for (int cf = 0; cf < 2; ++cf)
                #pragma unroll
                for (int p = 0; p < 3; ++p)
                    acc[tt][cf][p] = (i32x4){0, 0, 0, 0};

        uint2 ar[3][4];                 // rolling A buffers (static mod-3 idx)
        #pragma unroll
        for (int tt = 0; tt < 4; ++tt) {
            ar[0][tt] = *reinterpret_cast<const uint2*>(aP + tt * TSH);
            ar[1][tt] = *reinterpret_cast<const uint2*>(aP + tt * TSH + 512);
        }

        #pragma unroll
        for (int kt = 0; kt < NKT; ++kt) {
            if (kt + 2 < NKT) {         // prefetch 2 k-steps ahead
                #pragma unroll
                for (int tt = 0; tt < 4; ++tt)
                    ar[(kt + 2) % 3][tt] = *reinterpret_cast<const uint2*>(
                        aP + tt * TSH + (kt + 2) * 512);
            }
            uint4 bf[2][3];
            #pragma unroll
            for (int cf = 0; cf < 2; ++cf)
                #pragma unroll
                for (int p = 0; p < 3; ++p)
                    bf[cf][p] = *reinterpret_cast<const uint4*>(&Bq[bO[cf][p] + kt * 64]);
            uint4 af[4];
            #pragma unroll
            for (int tt = 0; tt < 4; ++tt)
                af[tt] = unp(ar[kt % 3][tt]);

            __builtin_amdgcn_s_setprio(1);
            #pragma unroll
            for (int tt = 0; tt < 4; ++tt)
                #pragma unroll
                for (int cf = 0; cf < 2; ++cf)
                    #pragma unroll
                    for (int p = 0; p < 3; ++p)
                        acc[tt][cf][p] = __builtin_amdgcn_mfma_i32_16x16x64_i8(
                            __builtin_bit_cast(i32x4, af[tt]),
                            __builtin_bit_cast(i32x4, bf[cf][p]),
                            acc[tt][cf][p], 0, 0, 0);
            __builtin_amdgcn_s_setprio(0);
        }
        aP += 4 * TSH;

        // LIF for the 4 timesteps; pack 4 spike bytes -> one u32 store (Z1T)
        #pragma unroll
        for (int tt = 0; tt < 4; ++tt) {
            const int t = 4 * g + tt;
            #pragma unroll
            for (int cf = 0; cf < 2; ++cf) {
                u32 zw = 0;
                #pragma unroll
                for (int q = 0; q < 4; ++q) {
                    const int k = cf * 4 + q;
                    const float c1 = fmaf(s1, (float)acc[tt][cf][0][q],
                                     fmaf(s2, (float)acc[tt][cf][1][q],
                                     fmaf(s3, (float)acc[tt][cf][2][q],
                                          cf ? bb1 : bb0)));
                    const float vd = vS[k] + 0.1f * ((0.0f - vS[k]) + cS[k]);
                    const float id = cS[k] - 0.2f * cS[k];
                    const bool  sp = vd > 1.0f;
                    zw |= (sp ? 1u : 0u) << (8 * q);
                    vS[k] = sp ? 0.0f : vd;
                    cS[k] = id + c1;
                }
                u32* dst = reinterpret_cast<u32*>(
                    Z1T + (size_t)(n0 + cf * 16 + lr) * M_TOT
                        + (size_t)t * B_SZ + b0 + w * 16 + ls * 4);
                __builtin_nontemporal_store(zw, dst);
            }
        }
    }
}

// ---------------- GEMM2: C2T[o][m] from Z1T[n][m] --------------------------
__global__ __launch_bounds__(256) void gemm2_f32(
    const u8* __restrict__ Z1T, const float* __restrict__ W2,
    const float* __restrict__ b2, float* __restrict__ C2T)
{
    __shared__ float ws[N_OUT * N_HID];   // 10 KB
    const int tid = threadIdx.x;
    const int m = blockIdx.x * 256 + tid;

    for (int i = tid; i < N_OUT * N_HID; i += 256) ws[i] = W2[i];
    __syncthreads();

    float acc[N_OUT];
    #pragma unroll
    for (int o = 0; o < N_OUT; ++o) acc[o] = b2[o];

    const u8* zp = Z1T + m;
    for (int n0 = 0; n0 < N_HID; n0 += 8) {        // 8 independent loads (ILP)
        float zf[8];
        #pragma unroll
        for (int j = 0; j < 8; ++j)
            zf[j] = (float)zp[(size_t)(n0 + j) * M_TOT];
        #pragma unroll
        for (int o = 0; o < N_OUT; ++o) {          // groups-of-4 ascending n:
            acc[o] += zf[0] * ws[o * N_HID + n0 + 0] + zf[1] * ws[o * N_HID + n0 + 1]
                    + zf[2] * ws[o * N_HID + n0 + 2] + zf[3] * ws[o * N_HID + n0 + 3];
            acc[o] += zf[4] * ws[o * N_HID + n0 + 4] + zf[5] * ws[o * N_HID + n0 + 5]
                    + zf[6] * ws[o * N_HID + n0 + 6] + zf[7] * ws[o * N_HID + n0 + 7];
        }
    }
    #pragma unroll
    for (int o = 0; o < N_OUT; ++o)
        C2T[(size_t)o * M_TOT + m] = acc[o];
}

// ---------------- LIF2: thread = (o,b); reads C2T, coalesced ---------------
__global__ __launch_bounds__(256) void lif2_kernel(
    const float* __restrict__ C2T, float* __restrict__ out)
{
    const int g = blockIdx.x * 256 + threadIdx.x;   // < 40960
    const int o = g >> 12;              // 0..9
    const int b = g & (B_SZ - 1);
    float v = 0.0f, cur = 0.0f, s = 0.0f;
    #pragma unroll
    for (int t = 0; t < T_STEPS; ++t) {
        const float c = C2T[(size_t)o * M_TOT + t * B_SZ + b];
        const float vd = v + 0.1f * ((0.0f - v) + cur);
        const float id = cur - 0.2f * cur;
        const bool  sp = vd > 1.0f;
        s += sp ? 1.0f : 0.0f;
        v = sp ? 0.0f : vd;
        cur = id + c;
    }
    out[b * N_OUT + o] = s;
}

extern "C" void kernel_launch(void* const* d_in, const int* in_sizes, int n_in,
                              void* d_out, int out_size, void* d_ws, size_t ws_size,
                              hipStream_t stream)
{
    const float* X  = (const float*)d_in[0];
    const float* W1 = (const float*)d_in[1];
    const float* b1 = (const float*)d_in[2];
    const float* W2 = (const float*)d_in[3];
    const float* b2 = (const float*)d_in[4];
    float* out = (float*)d_out;

    // ws: [Wq 0.64MB | pad->1MB][Xq4T 27.3MB][Z1T 16.8MB][C2T 2.6MB] ~48MB
    char* Wq = (char*)d_ws;
    u8*   Xq4T = (u8*)d_ws + (1 << 20);
    u8*   Z1T = Xq4T + (size_t)M_TOT * KNB;
    float* C2T = (float*)(Z1T + (size_t)M_TOT * N_HID);

    conv_x<<<(M_TOT * 52) / 256, 256, 0, stream>>>(X, Xq4T);

    conv_w3<<<(N_HID * KP8) / 256, 256, 0, stream>>>(W1, Wq);

    gemm1_lif1<<<512, 256, 0, stream>>>(Xq4T, (const u8*)Wq, b1, Z1T);

    gemm2_f32<<<M_TOT / 256, 256, 0, stream>>>(Z1T, W2, b2, C2T);

    lif2_kernel<<<(B_SZ * N_OUT) / 256, 256, 0, stream>>>(C2T, out);
}